// Round 7
// baseline (22.468 us; speedup 1.0000x reference)
//
#include <hip/hip_runtime.h>

// CLUB loss, algebraically collapsed to O(N*d) streaming reductions:
//   loss = -0.5/N * S_pos + 0.5/N^2 * ( dot(S_invv,S_x2) - 2*dot(S_muinvv,S_x) + N*S_c )
// Single kernel, last-block-done, fence-free (atomics only across blocks).
// R7: float4 mu/logvar loads (1KB/instr), 512 blocks (8 waves/CU),
//     shfl-based reduction (3 barriers instead of 12).

#define NROWS 16384
#define DDIM  64
#define GRID  512           // 32-row tile per block
#define ROWS  32
#define NCOL  258           // 4*64 vector partials + {S_c, S_pos}
#define NREP  8             // accumulator replicas (64-way contention each)

__device__ double g_acc[NREP * NCOL];   // zero at module load; self-reset each run
__device__ int    g_counter = 0;

__global__ __launch_bounds__(256) void club_fused(const float* __restrict__ x,
                                                  const float* __restrict__ mu,
                                                  const float* __restrict__ logvar,
                                                  float* __restrict__ out) {
    __shared__ __align__(16) float xt[ROWS * 68];   // [row][68]: rows 272B (16B-aligned), 4-bank skew
    __shared__ double red[64 * 16];                 // [wave*16+q][stat*4+sub] = 8 KB
    __shared__ double sred[8];
    __shared__ double S[NCOL];
    __shared__ int    is_last;

    const int tid = threadIdx.x;
    const int bid = blockIdx.x;
    const int i0  = bid * ROWS;
    const int b   = i0 >> 10;          // h*w = 1024 rows per batch image
    const int hw0 = i0 & 1023;         // multiple of 32 -> 128B aligned

    // ---- stage x[b, :, hw0:hw0+32] into LDS, transposed to row-major [r][d] ----
    const float* xb = x + (size_t)b * 65536 + hw0;
    #pragma unroll
    for (int c = 0; c < 2; ++c) {
        const int f  = tid + 256 * c;          // 512 float4s
        const int dd = f >> 3, j4 = (f & 7) * 4;
        const float4 v = *(const float4*)(xb + (size_t)dd * 1024 + j4);
        xt[(j4 + 0) * 68 + dd] = v.x;
        xt[(j4 + 1) * 68 + dd] = v.y;
        xt[(j4 + 2) * 68 + dd] = v.z;
        xt[(j4 + 3) * 68 + dd] = v.w;
    }
    __syncthreads();

    // ---- per-thread partials: thread = (d-quad q, row rw/rw+16) ----
    const int q  = tid & 15;           // d = 4q + i
    const int rw = tid >> 4;

    double ax[4]  = {0,0,0,0}, ax2[4]  = {0,0,0,0};
    double aiv[4] = {0,0,0,0}, amiv[4] = {0,0,0,0};
    double ac = 0.0, apos = 0.0;

    #pragma unroll
    for (int c = 0; c < 2; ++c) {
        const int r = rw + 16 * c;
        const float4 xv4 = *(const float4*)(&xt[r * 68 + 4 * q]);              // 256B/16-lane group
        const float4 m4  = *(const float4*)(mu     + (size_t)(i0 + r) * DDIM + 4 * q);  // 1KB/wave
        const float4 l4  = *(const float4*)(logvar + (size_t)(i0 + r) * DDIM + 4 * q);
        const float xs[4] = {xv4.x, xv4.y, xv4.z, xv4.w};
        const float ms[4] = {m4.x,  m4.y,  m4.z,  m4.w};
        const float ls[4] = {l4.x,  l4.y,  l4.z,  l4.w};
        #pragma unroll
        for (int i = 0; i < 4; ++i) {
            const float iv = expf(-ls[i]);
            const float t2 = xs[i] - ms[i];
            ax[i]   += (double)xs[i];
            ax2[i]  += (double)(xs[i] * xs[i]);
            aiv[i]  += (double)iv;
            amiv[i] += (double)(ms[i] * iv);
            ac      += (double)(ms[i] * ms[i] * iv);
            apos    += (double)(t2 * t2 * iv);
        }
    }

    // ---- in-wave reduce: owner lanes of (q,i) are l, l+16, l+32, l+48 ----
    #pragma unroll
    for (int i = 0; i < 4; ++i) {
        ax[i]   += __shfl_xor(ax[i],   16, 64);  ax[i]   += __shfl_xor(ax[i],   32, 64);
        ax2[i]  += __shfl_xor(ax2[i],  16, 64);  ax2[i]  += __shfl_xor(ax2[i],  32, 64);
        aiv[i]  += __shfl_xor(aiv[i],  16, 64);  aiv[i]  += __shfl_xor(aiv[i],  32, 64);
        amiv[i] += __shfl_xor(amiv[i], 16, 64);  amiv[i] += __shfl_xor(amiv[i], 32, 64);
    }
    #pragma unroll
    for (int off = 1; off < 64; off <<= 1) {
        ac   += __shfl_xor(ac,   off, 64);
        apos += __shfl_xor(apos, off, 64);
    }

    const int wave = tid >> 6;
    const int lane = tid & 63;
    if (lane < 16) {
        double* rp = &red[(wave * 16 + lane) * 16];
        #pragma unroll
        for (int i = 0; i < 4; ++i) {
            rp[0 * 4 + i] = ax[i];  rp[1 * 4 + i] = ax2[i];
            rp[2 * 4 + i] = aiv[i]; rp[3 * 4 + i] = amiv[i];
        }
    }
    if (lane == 0) { sred[wave * 2] = ac; sred[wave * 2 + 1] = apos; }
    __syncthreads();

    // ---- cross-wave fan-in: one atomic round (258 f64 atomics / block) ----
    double* acc = g_acc + (size_t)(bid & (NREP - 1)) * NCOL;
    if (tid < 64) {                         // thread t -> d = t; q = t>>2, sub = t&3
        const int qq = tid >> 2, sub = tid & 3;
        #pragma unroll
        for (int s = 0; s < 4; ++s) {
            double v = 0.0;
            #pragma unroll
            for (int W = 0; W < 4; ++W) v += red[(W * 16 + qq) * 16 + s * 4 + sub];
            atomicAdd(&acc[s * 64 + tid], v);
        }
    } else if (tid == 64) {
        atomicAdd(&acc[256], sred[0] + sred[2] + sred[4] + sred[6]);
        atomicAdd(&acc[257], sred[1] + sred[3] + sred[5] + sred[7]);
    }

    // ---- last-block election (fence-free release: drain own atomics) ----
    asm volatile("s_waitcnt vmcnt(0)" ::: "memory");
    __syncthreads();
    if (tid == 0) {
        is_last = (atomicAdd(&g_counter, 1) == GRID - 1);
        if (is_last) atomicExch(&g_counter, 0);   // reset for next replay
    }
    __syncthreads();
    if (!is_last) return;

    // ---- O(1) tail: coherent gather + reset via agent-scope atomics ----
    for (int c = tid; c < NCOL; c += 256) {
        double s = 0.0;
        #pragma unroll
        for (int r = 0; r < NREP; ++r) {
            s += __hip_atomic_load(&g_acc[r * NCOL + c],
                                   __ATOMIC_RELAXED, __HIP_MEMORY_SCOPE_AGENT);
            __hip_atomic_store(&g_acc[r * NCOL + c], 0.0,
                               __ATOMIC_RELAXED, __HIP_MEMORY_SCOPE_AGENT);
        }
        S[c] = s;
    }
    __syncthreads();

    // ---- final dot + scalar ----
    if (tid < 64) {
        double term = S[128 + tid] * S[64 + tid] - 2.0 * S[192 + tid] * S[tid];
        #pragma unroll
        for (int off = 32; off > 0; off >>= 1) term += __shfl_down(term, off, 64);
        if (tid == 0) {
            const double Nd   = (double)NROWS;
            const double sumD = term + Nd * S[256];
            out[0] = (float)(-0.5 / Nd * S[257] + 0.5 / (Nd * Nd) * sumD);
        }
    }
}

extern "C" void kernel_launch(void* const* d_in, const int* in_sizes, int n_in,
                              void* d_out, int out_size, void* d_ws, size_t ws_size,
                              hipStream_t stream) {
    const float* x      = (const float*)d_in[0];
    const float* mu     = (const float*)d_in[1];
    const float* logvar = (const float*)d_in[2];
    float* out = (float*)d_out;

    club_fused<<<GRID, 256, 0, stream>>>(x, mu, logvar, out);
}